// Round 8
// baseline (663.670 us; speedup 1.0000x reference)
//
#include <hip/hip_runtime.h>

// Quantized vector-matrix multiply: out[n] = sum_k (x[k]-Xzp)*Xs * (y[k,n]-Yzp)*Ys
// Exact-integer reformulation:
//   out[n] = Xs*Ys * ( sum_k xs[k]*y[k,n] - Yzp*sum_k xs[k] ),  xs = x - X_ZP
// Full-K |acc| ~ 1.8e8 -> int32-exact across all 128 split-K contributions.
//
// R11->R12: CACHE-POLICY PROBE, SAFE MECHANISM. R11's raw-asm counted-vmcnt
// pipeline failed correctness (absmax 8e5) -- the policy theory is untested,
// not refuted. This version swaps ONLY the load instruction of the proven R10
// kernel (656 us) for __builtin_amdgcn_raw_buffer_load_b128 with aux=19
// (GLC|SLC|SCC -> sc0 nt sc1 on gfx950: system-scope, non-temporal, no
// L1/L2 allocation). The compiler tracks these loads in vmcnt and inserts all
// waits itself -- cache-policy bits cannot affect correctness on read-only
// data, so worst case is a clean null A/B vs R10. __has_builtin fallback
// compiles to exactly R10. Epilogue: proven int32 atomicAdd accumulator +
// tiny scale kernel; corr computed block-uniform after the loop.

constexpr int K = 8192;
constexpr int N = 16384;
constexpr float X_SCALE = 0.0215f;
constexpr int   X_ZP    = -25;
constexpr float Y_SCALE = 0.0176f;
constexpr int   Y_ZP    = 18;

constexpr int BLOCK = 256;
constexpr int COLS_PER_BLOCK = 1024;           // int32 columns per block (4 KiB/row)
constexpr int NBLK_N = N / COLS_PER_BLOCK;     // 16
constexpr int SPLIT_K = 128;                   // 2048 blocks -> 8 blocks/CU
constexpr int KCHUNK = K / SPLIT_K;            // 64 rows per block
constexpr int N4 = N / 4;                      // 4096 ivec4 per row
constexpr int ROW_BYTES = N4 * 16;             // 65536

typedef int ivec4 __attribute__((ext_vector_type(4)));

#if defined(__has_builtin)
#if __has_builtin(__builtin_amdgcn_make_buffer_rsrc) && __has_builtin(__builtin_amdgcn_raw_buffer_load_b128)
#define USE_BUF_POLICY 1
#endif
#endif

__global__ __launch_bounds__(BLOCK, 8) void qgemv_fused(const int* __restrict__ x,
                                                        const int* __restrict__ y,
                                                        int* __restrict__ acc) {
    __shared__ int xs[KCHUNK];

    const int nb = blockIdx.x % NBLK_N;
    const int kc = blockIdx.x / NBLK_N;
    const int k0 = kc * KCHUNK;

    if (threadIdx.x < KCHUNK)
        xs[threadIdx.x] = x[k0 + threadIdx.x] - X_ZP;
    __syncthreads();

    const int col4 = nb * (COLS_PER_BLOCK / 4) + threadIdx.x;

#ifdef USE_BUF_POLICY
    // SRSRC over y: stride 0, num_records = 512 MiB (exact buffer size, HW
    // bounds-checked), word3 = raw-dword flags. Built once, wave-uniform.
    const auto rsrc = __builtin_amdgcn_make_buffer_rsrc((void*)y, (short)0,
                                                        0x20000000, 0x00020000);
    // Byte offset of row k0, this thread's 16 B slice. Max < 2^29, fits int.
    const int boff0 = (k0 * N4 + col4) * 16;
#else
    const ivec4* __restrict__ yv = (const ivec4*)y + (size_t)k0 * N4 + col4;
#endif

    // Per-block rotation phase (order-independent sum): spread concurrent blocks'
    // instantaneous footprint across HBM interleave units. (Kept identical to R10.)
    const int r0 = (13 * kc + 7 * nb) & (KCHUNK - 1);

    int acc0 = 0, acc1 = 0, acc2 = 0, acc3 = 0;

#pragma unroll 8
    for (int i = 0; i < KCHUNK; ++i) {
        int k = r0 + i;
        if (k >= KCHUNK) k -= KCHUNK;
#ifdef USE_BUF_POLICY
        // aux = 19 = GLC(1)|SLC(2)|SCC(16) -> "sc0 nt sc1": system scope,
        // non-temporal, no L1/L2 allocation. Compiler-tracked (vmcnt) load;
        // policy bits cannot affect correctness.
        ivec4 v = __builtin_amdgcn_raw_buffer_load_b128(rsrc, boff0 + k * ROW_BYTES,
                                                        0, 19);
#else
        ivec4 v = __builtin_nontemporal_load(&yv[(size_t)k * N4]);
#endif
        int a = xs[k];
        acc0 += a * v.x;
        acc1 += a * v.y;
        acc2 += a * v.z;
        acc3 += a * v.w;
    }

    // Block-uniform zero-point correction, off the critical path.
    int sx = 0;
#pragma unroll
    for (int i = 0; i < KCHUNK; ++i) sx += xs[i];
    const int corr = Y_ZP * sx;

    // Exact int32 accumulation across the 128 k-chunks via native atomics.
    int* o = acc + 4 * (size_t)col4;
    atomicAdd(o + 0, acc0 - corr);
    atomicAdd(o + 1, acc1 - corr);
    atomicAdd(o + 2, acc2 - corr);
    atomicAdd(o + 3, acc3 - corr);
}

// Tiny finish: scale int sums to fp32. 16 blocks x 256 threads, vec4 I/O.
__global__ __launch_bounds__(BLOCK) void qgemv_finish(const ivec4* __restrict__ acc,
                                                      float* __restrict__ out) {
    const int t = blockIdx.x * BLOCK + threadIdx.x;   // 0 .. N4-1
    ivec4 v = acc[t];
    const float s = X_SCALE * Y_SCALE;
    float4 o;
    o.x = s * (float)v.x;
    o.y = s * (float)v.y;
    o.z = s * (float)v.z;
    o.w = s * (float)v.w;
    ((float4*)out)[t] = o;
}

extern "C" void kernel_launch(void* const* d_in, const int* in_sizes, int n_in,
                              void* d_out, int out_size, void* d_ws, size_t ws_size,
                              hipStream_t stream) {
    const int* x = (const int*)d_in[0];
    const int* y = (const int*)d_in[1];
    float* out = (float*)d_out;
    int* acc = (int*)d_ws;                     // first 64 KB of workspace

    // Zero the accumulator (async, stream-ordered, graph-capturable).
    hipMemsetAsync(acc, 0, (size_t)N * sizeof(int), stream);
    qgemv_fused<<<SPLIT_K * NBLK_N, BLOCK, 0, stream>>>(x, y, acc);
    qgemv_finish<<<N4 / BLOCK, BLOCK, 0, stream>>>((const ivec4*)acc, out);
}